// Round 2
// baseline (130.747 us; speedup 1.0000x reference)
//
#include <hip/hip_runtime.h>
#include <hip/hip_bf16.h>
#include <stdint.h>

#define AS1 __attribute__((address_space(1)))
#define AS3 __attribute__((address_space(3)))

typedef __attribute__((ext_vector_type(8))) short bf16x8_t;
typedef __attribute__((ext_vector_type(4))) float f32x4_t;

#define DDIM 1024
#define BM 128
#define BN 128
#define BK 32

// fp32 -> bf16 round-to-nearest-even (unbiased; truncation's bias would eat
// ~80% of the 0.165 absmax budget over K=1024).
static __device__ inline ushort f32_to_bf16_rne(float f) {
  union { float f; uint32_t u; } v;
  v.f = f;
  v.u += 0x7FFFu + ((v.u >> 16) & 1u);
  return (ushort)(v.u >> 16);
}

// ---------------------------------------------------------------------------
// One-time transpose+convert: Wt[n][k] = bf16(W[k][n]), W fp32 1024x1024.
// LDS-tiled, 16B-coalesced global read and write. Wt = 2 MB in d_ws.
// ---------------------------------------------------------------------------
__global__ __launch_bounds__(256) void transpose_w(const float* __restrict__ W,
                                                   ushort* __restrict__ Wt) {
  __shared__ float tile[64][65];  // +1 pad: column reads cycle all 32 banks
  const int t  = threadIdx.x;
  const int bk = blockIdx.x;  // k-tile of W
  const int bn = blockIdx.y;  // n-tile of W
#pragma unroll
  for (int s = 0; s < 4; ++s) {
    const int slot = (s << 8) + t;
    const int r    = slot >> 4;         // 0..63
    const int c4   = (slot & 15) << 2;  // 0..60
    const float4 v = *(const float4*)(W + (size_t)(bk * 64 + r) * DDIM + bn * 64 + c4);
    tile[r][c4 + 0] = v.x; tile[r][c4 + 1] = v.y;
    tile[r][c4 + 2] = v.z; tile[r][c4 + 3] = v.w;
  }
  __syncthreads();
#pragma unroll
  for (int s = 0; s < 2; ++s) {
    const int slot = (s << 8) + t;
    const int n    = slot >> 3;        // 0..63
    const int k8   = (slot & 7) << 3;  // 0..56
    union { ushort h[8]; uint4 u; } tmp;
#pragma unroll
    for (int j = 0; j < 8; ++j) tmp.h[j] = f32_to_bf16_rne(tile[k8 + j][n]);
    *(uint4*)(Wt + (size_t)(bn * 64 + n) * DDIM + bk * 64 + k8) = tmp.u;
  }
}

// ---------------------------------------------------------------------------
// C[fp32] = X[fp32] * Wt^T, computed in bf16 MFMA (threshold 0.165 >> bf16
// error ~0.015). 128x128 tile, BK=32, 4 waves, 4x4 frags of 16x16x32.
// B stages via global_load_lds (Wt already bf16); A stages via fp32 float4
// loads + RNE convert + ds_write_b128.
// ---------------------------------------------------------------------------
__global__ __launch_bounds__(256) void gemm_xw(const float* __restrict__ X,
                                               const ushort* __restrict__ Wt,
                                               float* __restrict__ C) {
  __shared__ __align__(16) ushort As[BM * BK];  // 8 KB bf16, 64 B rows
  __shared__ __align__(16) ushort Bs[BN * BK];  // 8 KB

  const int t    = threadIdx.x;
  const int wave = t >> 6;
  const int lane = t & 63;
  const int m0 = blockIdx.x * BM;
  const int n0 = blockIdx.y * BN;

  // B staging map (global_load_lds, wave-uniform base + lane*16):
  // issue i covers rows [i*64, i*64+64); LDS byte = wave*1024 + lane*16
  // == (row - i*64)*64 + kchunk*16  (verified identity).
  const int srow  = (wave << 4) + (lane >> 2);
  const int skcol = (lane & 3) << 3;
  const ushort* bptr0 = Wt + (size_t)(n0 + srow) * DDIM + skcol;
  const ushort* bptr1 = Wt + (size_t)(n0 + 64 + srow) * DDIM + skcol;

  // A staging map (manual): thread t handles row t>>2 (and +64), k-chunk (t&3)*8.
  const int ar = t >> 2;          // 0..63
  const int ak = (t & 3) << 3;    // 0,8,16,24
  const float* aptr0 = X + (size_t)(m0 + ar) * DDIM + ak;
  const float* aptr1 = X + (size_t)(m0 + 64 + ar) * DDIM + ak;
  ushort* asw0 = &As[(ar << 5) + ak];
  ushort* asw1 = &As[((ar + 64) << 5) + ak];

  // Wave quadrant of the 128x128 C tile.
  const int wr = (wave >> 1) << 6;
  const int wc = (wave & 1) << 6;
  const int fr = lane & 15;   // A row / B col within 16
  const int fq = lane >> 4;   // quad -> k offset fq*8

  f32x4_t acc[4][4] = {};

  AS3 char* ldsB = (AS3 char*)Bs;
  const int woff = wave << 10;

  for (int kt = 0; kt < DDIM; kt += BK) {
    // A fp32 loads into regs before the barrier (off critical LDS path).
    const float4 a00 = *(const float4*)(aptr0);
    const float4 a01 = *(const float4*)(aptr0 + 4);
    const float4 a10 = *(const float4*)(aptr1);
    const float4 a11 = *(const float4*)(aptr1 + 4);
    aptr0 += BK; aptr1 += BK;

    __syncthreads();  // previous tile's ds_reads done before overwrite

    __builtin_amdgcn_global_load_lds((const AS1 void*)bptr0, (AS3 void*)(ldsB + woff),        16, 0, 0);
    __builtin_amdgcn_global_load_lds((const AS1 void*)bptr1, (AS3 void*)(ldsB + 4096 + woff), 16, 0, 0);
    bptr0 += BK; bptr1 += BK;

    union { ushort h[8]; bf16x8_t v; } c0, c1;
    c0.h[0] = f32_to_bf16_rne(a00.x); c0.h[1] = f32_to_bf16_rne(a00.y);
    c0.h[2] = f32_to_bf16_rne(a00.z); c0.h[3] = f32_to_bf16_rne(a00.w);
    c0.h[4] = f32_to_bf16_rne(a01.x); c0.h[5] = f32_to_bf16_rne(a01.y);
    c0.h[6] = f32_to_bf16_rne(a01.z); c0.h[7] = f32_to_bf16_rne(a01.w);
    c1.h[0] = f32_to_bf16_rne(a10.x); c1.h[1] = f32_to_bf16_rne(a10.y);
    c1.h[2] = f32_to_bf16_rne(a10.z); c1.h[3] = f32_to_bf16_rne(a10.w);
    c1.h[4] = f32_to_bf16_rne(a11.x); c1.h[5] = f32_to_bf16_rne(a11.y);
    c1.h[6] = f32_to_bf16_rne(a11.z); c1.h[7] = f32_to_bf16_rne(a11.w);
    *(bf16x8_t*)asw0 = c0.v;
    *(bf16x8_t*)asw1 = c1.v;

    __syncthreads();  // drains vmcnt (B) + lgkmcnt (A writes)

    bf16x8_t af[4], bfr[4];
#pragma unroll
    for (int mi = 0; mi < 4; ++mi)
      af[mi] = *(const bf16x8_t*)&As[((wr + (mi << 4) + fr) << 5) + (fq << 3)];
#pragma unroll
    for (int ni = 0; ni < 4; ++ni)
      bfr[ni] = *(const bf16x8_t*)&Bs[((wc + (ni << 4) + fr) << 5) + (fq << 3)];
#pragma unroll
    for (int mi = 0; mi < 4; ++mi)
#pragma unroll
      for (int ni = 0; ni < 4; ++ni)
        acc[mi][ni] = __builtin_amdgcn_mfma_f32_16x16x32_bf16(af[mi], bfr[ni], acc[mi][ni], 0, 0, 0);
  }

  // Epilogue, fp32 out. C/D layout: col = lane&15, row = (lane>>4)*4 + reg.
#pragma unroll
  for (int mi = 0; mi < 4; ++mi) {
#pragma unroll
    for (int r = 0; r < 4; ++r) {
      const int row = m0 + wr + (mi << 4) + (fq << 2) + r;
      float* crow = C + (size_t)row * DDIM + n0 + wc + fr;
#pragma unroll
      for (int ni = 0; ni < 4; ++ni)
        crow[ni << 4] = acc[mi][ni][r];
    }
  }
}

// ---------------------------------------------------------------------------
// softmax over a size-1 sequence axis == 1.0 exactly, so
// out = v = x @ kernel[2]. q/k and the score matrix are dead code.
// ---------------------------------------------------------------------------
extern "C" void kernel_launch(void* const* d_in, const int* in_sizes, int n_in,
                              void* d_out, int out_size, void* d_ws, size_t ws_size,
                              hipStream_t stream) {
  const float* x    = (const float*)d_in[0];
  const float* kern = (const float*)d_in[1];
  const float* W = kern + (size_t)2 * DDIM * DDIM;  // kernel[2] — V projection
  ushort* Wt = (ushort*)d_ws;                       // 2 MiB scratch
  const int M = in_sizes[0] / DDIM;                 // 8192

  transpose_w<<<dim3(DDIM / 64, DDIM / 64), 256, 0, stream>>>(W, Wt);
  gemm_xw<<<dim3(M / BM, DDIM / BN), 256, 0, stream>>>(x, Wt, (float*)d_out);
}

// Round 3
// 117.817 us; speedup vs baseline: 1.1097x; 1.1097x over previous
//
#include <hip/hip_runtime.h>
#include <hip/hip_bf16.h>
#include <stdint.h>

#define AS1 __attribute__((address_space(1)))
#define AS3 __attribute__((address_space(3)))

typedef __attribute__((ext_vector_type(8))) short bf16x8_t;
typedef __attribute__((ext_vector_type(4))) float f32x4_t;

#define DDIM 1024
#define WT_ELEMS ((size_t)DDIM * DDIM)          // 1 Mi bf16 = 2 MiB
#define XB_ELEMS ((size_t)8192 * DDIM)          // 8 Mi bf16 = 16 MiB

// fp32 -> bf16 round-to-nearest-even (truncation bias over K=1024 would eat
// most of the 0.165 absmax budget).
static __device__ inline ushort f32_to_bf16_rne(float f) {
  union { float f; uint32_t u; } v;
  v.f = f;
  v.u += 0x7FFFu + ((v.u >> 16) & 1u);
  return (ushort)(v.u >> 16);
}

// ---------------------------------------------------------------------------
// One-time transpose+convert: Wt[n][k] = bf16(W[k][n]), W fp32 1024x1024.
// ---------------------------------------------------------------------------
__global__ __launch_bounds__(256) void transpose_w(const float* __restrict__ W,
                                                   ushort* __restrict__ Wt) {
  __shared__ float tile[64][65];
  const int t  = threadIdx.x;
  const int bk = blockIdx.x;
  const int bn = blockIdx.y;
#pragma unroll
  for (int s = 0; s < 4; ++s) {
    const int slot = (s << 8) + t;
    const int r    = slot >> 4;
    const int c4   = (slot & 15) << 2;
    const float4 v = *(const float4*)(W + (size_t)(bk * 64 + r) * DDIM + bn * 64 + c4);
    tile[r][c4 + 0] = v.x; tile[r][c4 + 1] = v.y;
    tile[r][c4 + 2] = v.z; tile[r][c4 + 3] = v.w;
  }
  __syncthreads();
#pragma unroll
  for (int s = 0; s < 2; ++s) {
    const int slot = (s << 8) + t;
    const int n    = slot >> 3;
    const int k8   = (slot & 7) << 3;
    union { ushort h[8]; uint4 u; } tmp;
#pragma unroll
    for (int j = 0; j < 8; ++j) tmp.h[j] = f32_to_bf16_rne(tile[k8 + j][n]);
    *(uint4*)(Wt + (size_t)(bn * 64 + n) * DDIM + bk * 64 + k8) = tmp.u;
  }
}

// ---------------------------------------------------------------------------
// One-time convert: Xb = bf16(X), 8192x1024. Each thread: 8 floats -> 16B out.
// ---------------------------------------------------------------------------
__global__ __launch_bounds__(256) void convert_x(const float* __restrict__ X,
                                                 ushort* __restrict__ Xb) {
  const size_t i = ((size_t)blockIdx.x * 256 + threadIdx.x) << 3;
  const float4 v0 = *(const float4*)(X + i);
  const float4 v1 = *(const float4*)(X + i + 4);
  union { ushort h[8]; uint4 u; } o;
  o.h[0] = f32_to_bf16_rne(v0.x); o.h[1] = f32_to_bf16_rne(v0.y);
  o.h[2] = f32_to_bf16_rne(v0.z); o.h[3] = f32_to_bf16_rne(v0.w);
  o.h[4] = f32_to_bf16_rne(v1.x); o.h[5] = f32_to_bf16_rne(v1.y);
  o.h[6] = f32_to_bf16_rne(v1.z); o.h[7] = f32_to_bf16_rne(v1.w);
  *(uint4*)(Xb + i) = o.u;
}

// ---------------------------------------------------------------------------
// Main GEMM: C[fp32 8192x1024] = Xb * Wt^T, all-bf16 staging (m97 structure).
// BM=64, BN=128, BK=32 -> grid 128x8 = 1024 blocks = 4 blocks/CU = 16 waves/CU.
// 4 waves in 2x2 over (64,128): each wave 32x64 = 2x4 frags of 16x16x32.
// LDS staged via global_load_lds width=16 with XOR-swizzled chunk mapping:
// slot s (16B units) holds global chunk (row = s>>2, c = (s&3) ^ ((row>>1)&3)),
// making fragment ds_read_b128 exactly 2-way per bank-quad (free, m136).
// ---------------------------------------------------------------------------
__global__ __launch_bounds__(256, 4) void gemm_bb(const ushort* __restrict__ Xb,
                                                  const ushort* __restrict__ Wt,
                                                  float* __restrict__ C) {
  __shared__ __align__(16) ushort As[64 * 32];   // 4 KB
  __shared__ __align__(16) ushort Bs[128 * 32];  // 8 KB

  const int t    = threadIdx.x;
  const int wave = t >> 6;
  const int lane = t & 63;
  const int m0 = blockIdx.x * 64;
  const int n0 = blockIdx.y * 128;

  // Staging map: slot s = wave*64 + lane covers row sr = s>>2 of a 64-row
  // region; swizzled chunk sc = (s&3) ^ ((sr>>1)&3). Global addr is per-lane,
  // LDS addr is the mandatory wave-uniform base + lane*16.
  const int s  = (wave << 6) + lane;
  const int sr = s >> 2;
  const int sc = (s & 3) ^ ((sr >> 1) & 3);
  const ushort* aptr  = Xb + (size_t)(m0 + sr) * DDIM + (sc << 3);
  const ushort* bptr0 = Wt + (size_t)(n0 + sr) * DDIM + (sc << 3);
  const ushort* bptr1 = Wt + (size_t)(n0 + 64 + sr) * DDIM + (sc << 3);

  AS3 char* ldsA = (AS3 char*)As;
  AS3 char* ldsB = (AS3 char*)Bs;
  const int woff = wave << 10;

  // Wave tile: 32 rows x 64 cols of the 64x128 block tile.
  const int wr = (wave >> 1) << 5;
  const int wc = (wave & 1) << 6;
  const int fr = lane & 15;
  const int fq = lane >> 4;

  f32x4_t acc[2][4] = {};

  for (int kt = 0; kt < DDIM; kt += 32) {
    __syncthreads();
    __builtin_amdgcn_global_load_lds((const AS1 void*)aptr,  (AS3 void*)(ldsA + woff),        16, 0, 0);
    __builtin_amdgcn_global_load_lds((const AS1 void*)bptr0, (AS3 void*)(ldsB + woff),        16, 0, 0);
    __builtin_amdgcn_global_load_lds((const AS1 void*)bptr1, (AS3 void*)(ldsB + 4096 + woff), 16, 0, 0);
    aptr += 32; bptr0 += 32; bptr1 += 32;
    __syncthreads();

    bf16x8_t af[2], bfr[4];
#pragma unroll
    for (int mi = 0; mi < 2; ++mi) {
      const int r = wr + (mi << 4) + fr;
      af[mi] = *(const bf16x8_t*)&As[(r << 5) + ((fq ^ ((r >> 1) & 3)) << 3)];
    }
#pragma unroll
    for (int ni = 0; ni < 4; ++ni) {
      const int r = wc + (ni << 4) + fr;
      bfr[ni] = *(const bf16x8_t*)&Bs[(r << 5) + ((fq ^ ((r >> 1) & 3)) << 3)];
    }
#pragma unroll
    for (int mi = 0; mi < 2; ++mi)
#pragma unroll
      for (int ni = 0; ni < 4; ++ni)
        acc[mi][ni] = __builtin_amdgcn_mfma_f32_16x16x32_bf16(af[mi], bfr[ni], acc[mi][ni], 0, 0, 0);
  }

  // Epilogue. C/D layout: col = lane&15, row = (lane>>4)*4 + reg.
#pragma unroll
  for (int mi = 0; mi < 2; ++mi) {
#pragma unroll
    for (int r = 0; r < 4; ++r) {
      const int row = m0 + wr + (mi << 4) + (fq << 2) + r;
      float* crow = C + (size_t)row * DDIM + n0 + wc + fr;
#pragma unroll
      for (int ni = 0; ni < 4; ++ni)
        crow[ni << 4] = acc[mi][ni][r];
    }
  }
}

// ---------------------------------------------------------------------------
// Fallback GEMM (round-2, known correct): in-loop fp32 A convert, BM=BN=128.
// Used only if ws_size can't hold Wt + Xb.
// ---------------------------------------------------------------------------
__global__ __launch_bounds__(256) void gemm_xw(const float* __restrict__ X,
                                               const ushort* __restrict__ Wt,
                                               float* __restrict__ C) {
  __shared__ __align__(16) ushort As[128 * 32];
  __shared__ __align__(16) ushort Bs[128 * 32];
  const int t    = threadIdx.x;
  const int wave = t >> 6;
  const int lane = t & 63;
  const int m0 = blockIdx.x * 128;
  const int n0 = blockIdx.y * 128;
  const int srow  = (wave << 4) + (lane >> 2);
  const int skcol = (lane & 3) << 3;
  const ushort* bptr0 = Wt + (size_t)(n0 + srow) * DDIM + skcol;
  const ushort* bptr1 = Wt + (size_t)(n0 + 64 + srow) * DDIM + skcol;
  const int ar = t >> 2;
  const int ak = (t & 3) << 3;
  const float* aptr0 = X + (size_t)(m0 + ar) * DDIM + ak;
  const float* aptr1 = X + (size_t)(m0 + 64 + ar) * DDIM + ak;
  ushort* asw0 = &As[(ar << 5) + ak];
  ushort* asw1 = &As[((ar + 64) << 5) + ak];
  const int wr = (wave >> 1) << 6;
  const int wc = (wave & 1) << 6;
  const int fr = lane & 15;
  const int fq = lane >> 4;
  f32x4_t acc[4][4] = {};
  AS3 char* ldsB = (AS3 char*)Bs;
  const int woff = wave << 10;
  for (int kt = 0; kt < DDIM; kt += 32) {
    const float4 a00 = *(const float4*)(aptr0);
    const float4 a01 = *(const float4*)(aptr0 + 4);
    const float4 a10 = *(const float4*)(aptr1);
    const float4 a11 = *(const float4*)(aptr1 + 4);
    aptr0 += 32; aptr1 += 32;
    __syncthreads();
    __builtin_amdgcn_global_load_lds((const AS1 void*)bptr0, (AS3 void*)(ldsB + woff),        16, 0, 0);
    __builtin_amdgcn_global_load_lds((const AS1 void*)bptr1, (AS3 void*)(ldsB + 4096 + woff), 16, 0, 0);
    bptr0 += 32; bptr1 += 32;
    union { ushort h[8]; bf16x8_t v; } c0, c1;
    c0.h[0] = f32_to_bf16_rne(a00.x); c0.h[1] = f32_to_bf16_rne(a00.y);
    c0.h[2] = f32_to_bf16_rne(a00.z); c0.h[3] = f32_to_bf16_rne(a00.w);
    c0.h[4] = f32_to_bf16_rne(a01.x); c0.h[5] = f32_to_bf16_rne(a01.y);
    c0.h[6] = f32_to_bf16_rne(a01.z); c0.h[7] = f32_to_bf16_rne(a01.w);
    c1.h[0] = f32_to_bf16_rne(a10.x); c1.h[1] = f32_to_bf16_rne(a10.y);
    c1.h[2] = f32_to_bf16_rne(a10.z); c1.h[3] = f32_to_bf16_rne(a10.w);
    c1.h[4] = f32_to_bf16_rne(a11.x); c1.h[5] = f32_to_bf16_rne(a11.y);
    c1.h[6] = f32_to_bf16_rne(a11.z); c1.h[7] = f32_to_bf16_rne(a11.w);
    *(bf16x8_t*)asw0 = c0.v;
    *(bf16x8_t*)asw1 = c1.v;
    __syncthreads();
    bf16x8_t af[4], bfr[4];
#pragma unroll
    for (int mi = 0; mi < 4; ++mi)
      af[mi] = *(const bf16x8_t*)&As[((wr + (mi << 4) + fr) << 5) + (fq << 3)];
#pragma unroll
    for (int ni = 0; ni < 4; ++ni)
      bfr[ni] = *(const bf16x8_t*)&Bs[((wc + (ni << 4) + fr) << 5) + (fq << 3)];
#pragma unroll
    for (int mi = 0; mi < 4; ++mi)
#pragma unroll
      for (int ni = 0; ni < 4; ++ni)
        acc[mi][ni] = __builtin_amdgcn_mfma_f32_16x16x32_bf16(af[mi], bfr[ni], acc[mi][ni], 0, 0, 0);
  }
#pragma unroll
  for (int mi = 0; mi < 4; ++mi)
#pragma unroll
    for (int r = 0; r < 4; ++r) {
      const int row = m0 + wr + (mi << 4) + (fq << 2) + r;
      float* crow = C + (size_t)row * DDIM + n0 + wc + fr;
#pragma unroll
      for (int ni = 0; ni < 4; ++ni)
        crow[ni << 4] = acc[mi][ni][r];
    }
}

// ---------------------------------------------------------------------------
// softmax over the size-1 sequence axis == 1.0 exactly -> out = x @ kernel[2].
// ---------------------------------------------------------------------------
extern "C" void kernel_launch(void* const* d_in, const int* in_sizes, int n_in,
                              void* d_out, int out_size, void* d_ws, size_t ws_size,
                              hipStream_t stream) {
  const float* x    = (const float*)d_in[0];
  const float* kern = (const float*)d_in[1];
  const float* W = kern + (size_t)2 * DDIM * DDIM;  // kernel[2] — V projection
  ushort* Wt = (ushort*)d_ws;
  const int M = in_sizes[0] / DDIM;  // 8192

  transpose_w<<<dim3(DDIM / 64, DDIM / 64), 256, 0, stream>>>(W, Wt);

  if (ws_size >= (WT_ELEMS + XB_ELEMS) * sizeof(ushort)) {
    ushort* Xb = (ushort*)d_ws + WT_ELEMS;
    convert_x<<<(unsigned)((size_t)M * DDIM / 8 / 256), 256, 0, stream>>>(x, Xb);
    gemm_bb<<<dim3(M / 64, DDIM / 128), 256, 0, stream>>>(Xb, Wt, (float*)d_out);
  } else {
    gemm_xw<<<dim3(M / 128, DDIM / 128), 256, 0, stream>>>(x, Wt, (float*)d_out);
  }
}

// Round 4
// 114.028 us; speedup vs baseline: 1.1466x; 1.0332x over previous
//
#include <hip/hip_runtime.h>
#include <hip/hip_bf16.h>
#include <stdint.h>

#define AS1 __attribute__((address_space(1)))
#define AS3 __attribute__((address_space(3)))

typedef __attribute__((ext_vector_type(8))) short bf16x8_t;
typedef __attribute__((ext_vector_type(4))) float f32x4_t;

#define DDIM 1024
#define WT_ELEMS ((size_t)DDIM * DDIM)   // 1 Mi bf16 = 2 MiB
#define XB_ELEMS ((size_t)8192 * DDIM)   // 8 Mi bf16 = 16 MiB

// fp32 -> bf16 round-to-nearest-even (truncation bias over K=1024 would eat
// most of the 0.165 absmax budget).
static __device__ inline ushort f32_to_bf16_rne(float f) {
  union { float f; uint32_t u; } v;
  v.f = f;
  v.u += 0x7FFFu + ((v.u >> 16) & 1u);
  return (ushort)(v.u >> 16);
}

// ---------------------------------------------------------------------------
// One-time transpose+convert: Wt[n][k] = bf16(W[k][n]), W fp32 1024x1024.
// ---------------------------------------------------------------------------
__global__ __launch_bounds__(256) void transpose_w(const float* __restrict__ W,
                                                   ushort* __restrict__ Wt) {
  __shared__ float tile[64][65];
  const int t  = threadIdx.x;
  const int bk = blockIdx.x;
  const int bn = blockIdx.y;
#pragma unroll
  for (int s = 0; s < 4; ++s) {
    const int slot = (s << 8) + t;
    const int r    = slot >> 4;
    const int c4   = (slot & 15) << 2;
    const float4 v = *(const float4*)(W + (size_t)(bk * 64 + r) * DDIM + bn * 64 + c4);
    tile[r][c4 + 0] = v.x; tile[r][c4 + 1] = v.y;
    tile[r][c4 + 2] = v.z; tile[r][c4 + 3] = v.w;
  }
  __syncthreads();
#pragma unroll
  for (int s = 0; s < 2; ++s) {
    const int slot = (s << 8) + t;
    const int n    = slot >> 3;
    const int k8   = (slot & 7) << 3;
    union { ushort h[8]; uint4 u; } tmp;
#pragma unroll
    for (int j = 0; j < 8; ++j) tmp.h[j] = f32_to_bf16_rne(tile[k8 + j][n]);
    *(uint4*)(Wt + (size_t)(bn * 64 + n) * DDIM + bk * 64 + k8) = tmp.u;
  }
}

// ---------------------------------------------------------------------------
// One-time convert: Xb = bf16(X), 8192x1024. Each thread: 8 floats -> 16B out.
// ---------------------------------------------------------------------------
__global__ __launch_bounds__(256) void convert_x(const float* __restrict__ X,
                                                 ushort* __restrict__ Xb) {
  const size_t i = ((size_t)blockIdx.x * 256 + threadIdx.x) << 3;
  const float4 v0 = *(const float4*)(X + i);
  const float4 v1 = *(const float4*)(X + i + 4);
  union { ushort h[8]; uint4 u; } o;
  o.h[0] = f32_to_bf16_rne(v0.x); o.h[1] = f32_to_bf16_rne(v0.y);
  o.h[2] = f32_to_bf16_rne(v0.z); o.h[3] = f32_to_bf16_rne(v0.w);
  o.h[4] = f32_to_bf16_rne(v1.x); o.h[5] = f32_to_bf16_rne(v1.y);
  o.h[6] = f32_to_bf16_rne(v1.z); o.h[7] = f32_to_bf16_rne(v1.w);
  *(uint4*)(Xb + i) = o.u;
}

// ---------------------------------------------------------------------------
// Main GEMM: C[fp32 8192x1024] = Xb * Wt^T.
// 512 threads (8 waves), 128x128 tile, BK=64 -> grid 64x8 = 512 blocks
// = 2 blocks/CU = 16 waves/CU, with m97's 256 B-staged-per-MFMA ratio and
// 2x the MFMA per barrier drain (16/wave/iter, 16 iters).
// Waves tiled 2x4 over (128,128): each wave 64x32 = 4x2 frags of 16x16x32.
// LDS rows are 128 B (64 bf16); chunk-XOR swizzle (c ^= row&7) makes every
// ds_read_b128 a uniform 8-touch/bank (conflict-free) while satisfying
// global_load_lds' mandatory "wave-uniform base + lane*16" LDS layout.
// ---------------------------------------------------------------------------
__global__ __launch_bounds__(512, 4) void gemm_bb(const ushort* __restrict__ Xb,
                                                  const ushort* __restrict__ Wt,
                                                  float* __restrict__ C) {
  __shared__ __align__(16) ushort As[128 * 64];  // 16 KB
  __shared__ __align__(16) ushort Bs[128 * 64];  // 16 KB

  const int t    = threadIdx.x;
  const int wave = t >> 6;
  const int lane = t & 63;
  const int m0 = blockIdx.x * 128;
  const int n0 = blockIdx.y * 128;

  // Staging map: slot s = wave*64+lane covers row sr = s>>3 (0..63) of a
  // 64-row half; chunk sc = (s&7) ^ (sr&7). Issue 1 covers rows 64..127
  // (same sc since (sr+64)&7 == sr&7). LDS dest = half*8192 + wave*1024
  // + lane*16 == slot*16 within the half (identity).
  const int s  = (wave << 6) + lane;
  const int sr = s >> 3;
  const int sc = (s & 7) ^ (sr & 7);
  const ushort* aptr0 = Xb + (size_t)(m0 + sr) * DDIM + (sc << 3);
  const ushort* aptr1 = aptr0 + (size_t)64 * DDIM;
  const ushort* bptr0 = Wt + (size_t)(n0 + sr) * DDIM + (sc << 3);
  const ushort* bptr1 = bptr0 + (size_t)64 * DDIM;

  AS3 char* ldsA = (AS3 char*)As;
  AS3 char* ldsB = (AS3 char*)Bs;
  const int woff = wave << 10;

  // Wave tile: 64 rows x 32 cols.
  const int wr = (wave >> 2) << 6;  // 0 or 64
  const int wc = (wave & 3) << 5;   // 0,32,64,96
  const int fr = lane & 15;
  const int fq = lane >> 4;

  f32x4_t acc[4][2] = {};

  for (int kt = 0; kt < DDIM; kt += 64) {
    __syncthreads();  // previous tile's ds_reads complete before overwrite
    __builtin_amdgcn_global_load_lds((const AS1 void*)aptr0, (AS3 void*)(ldsA + woff),        16, 0, 0);
    __builtin_amdgcn_global_load_lds((const AS1 void*)aptr1, (AS3 void*)(ldsA + 8192 + woff), 16, 0, 0);
    __builtin_amdgcn_global_load_lds((const AS1 void*)bptr0, (AS3 void*)(ldsB + woff),        16, 0, 0);
    __builtin_amdgcn_global_load_lds((const AS1 void*)bptr1, (AS3 void*)(ldsB + 8192 + woff), 16, 0, 0);
    aptr0 += 64; aptr1 += 64; bptr0 += 64; bptr1 += 64;
    __syncthreads();  // vmcnt(0) drain (m97 structure)

#pragma unroll
    for (int ks = 0; ks < 2; ++ks) {
      bf16x8_t af[4], bfr[2];
#pragma unroll
      for (int mi = 0; mi < 4; ++mi) {
        const int r = wr + (mi << 4) + fr;
        af[mi] = *(const bf16x8_t*)&As[(r << 6) + ((((ks << 2) + fq) ^ (r & 7)) << 3)];
      }
#pragma unroll
      for (int ni = 0; ni < 2; ++ni) {
        const int r = wc + (ni << 4) + fr;
        bfr[ni] = *(const bf16x8_t*)&Bs[(r << 6) + ((((ks << 2) + fq) ^ (r & 7)) << 3)];
      }
#pragma unroll
      for (int mi = 0; mi < 4; ++mi)
#pragma unroll
        for (int ni = 0; ni < 2; ++ni)
          acc[mi][ni] = __builtin_amdgcn_mfma_f32_16x16x32_bf16(af[mi], bfr[ni], acc[mi][ni], 0, 0, 0);
    }
  }

  // Epilogue. C/D layout: col = lane&15, row = (lane>>4)*4 + reg.
#pragma unroll
  for (int mi = 0; mi < 4; ++mi) {
#pragma unroll
    for (int r = 0; r < 4; ++r) {
      const int row = m0 + wr + (mi << 4) + (fq << 2) + r;
      float* crow = C + (size_t)row * DDIM + n0 + wc + fr;
      crow[0]  = acc[mi][0][r];
      crow[16] = acc[mi][1][r];
    }
  }
}

// ---------------------------------------------------------------------------
// Fallback GEMM (round-2, known correct) if ws can't hold Wt + Xb.
// ---------------------------------------------------------------------------
__global__ __launch_bounds__(256) void gemm_xw(const float* __restrict__ X,
                                               const ushort* __restrict__ Wt,
                                               float* __restrict__ C) {
  __shared__ __align__(16) ushort As[128 * 32];
  __shared__ __align__(16) ushort Bs[128 * 32];
  const int t    = threadIdx.x;
  const int wave = t >> 6;
  const int lane = t & 63;
  const int m0 = blockIdx.x * 128;
  const int n0 = blockIdx.y * 128;
  const int srow  = (wave << 4) + (lane >> 2);
  const int skcol = (lane & 3) << 3;
  const ushort* bptr0 = Wt + (size_t)(n0 + srow) * DDIM + skcol;
  const ushort* bptr1 = Wt + (size_t)(n0 + 64 + srow) * DDIM + skcol;
  const int ar = t >> 2;
  const int ak = (t & 3) << 3;
  const float* aptr0 = X + (size_t)(m0 + ar) * DDIM + ak;
  const float* aptr1 = X + (size_t)(m0 + 64 + ar) * DDIM + ak;
  ushort* asw0 = &As[(ar << 5) + ak];
  ushort* asw1 = &As[((ar + 64) << 5) + ak];
  const int wr = (wave >> 1) << 6;
  const int wc = (wave & 1) << 6;
  const int fr = lane & 15;
  const int fq = lane >> 4;
  f32x4_t acc[4][4] = {};
  AS3 char* ldsB = (AS3 char*)Bs;
  const int woff = wave << 10;
  for (int kt = 0; kt < DDIM; kt += 32) {
    const float4 a00 = *(const float4*)(aptr0);
    const float4 a01 = *(const float4*)(aptr0 + 4);
    const float4 a10 = *(const float4*)(aptr1);
    const float4 a11 = *(const float4*)(aptr1 + 4);
    aptr0 += 32; aptr1 += 32;
    __syncthreads();
    __builtin_amdgcn_global_load_lds((const AS1 void*)bptr0, (AS3 void*)(ldsB + woff),        16, 0, 0);
    __builtin_amdgcn_global_load_lds((const AS1 void*)bptr1, (AS3 void*)(ldsB + 4096 + woff), 16, 0, 0);
    bptr0 += 32; bptr1 += 32;
    union { ushort h[8]; bf16x8_t v; } c0, c1;
    c0.h[0] = f32_to_bf16_rne(a00.x); c0.h[1] = f32_to_bf16_rne(a00.y);
    c0.h[2] = f32_to_bf16_rne(a00.z); c0.h[3] = f32_to_bf16_rne(a00.w);
    c0.h[4] = f32_to_bf16_rne(a01.x); c0.h[5] = f32_to_bf16_rne(a01.y);
    c0.h[6] = f32_to_bf16_rne(a01.z); c0.h[7] = f32_to_bf16_rne(a01.w);
    c1.h[0] = f32_to_bf16_rne(a10.x); c1.h[1] = f32_to_bf16_rne(a10.y);
    c1.h[2] = f32_to_bf16_rne(a10.z); c1.h[3] = f32_to_bf16_rne(a10.w);
    c1.h[4] = f32_to_bf16_rne(a11.x); c1.h[5] = f32_to_bf16_rne(a11.y);
    c1.h[6] = f32_to_bf16_rne(a11.z); c1.h[7] = f32_to_bf16_rne(a11.w);
    *(bf16x8_t*)asw0 = c0.v;
    *(bf16x8_t*)asw1 = c1.v;
    __syncthreads();
    bf16x8_t af[4], bfr[4];
#pragma unroll
    for (int mi = 0; mi < 4; ++mi)
      af[mi] = *(const bf16x8_t*)&As[((wr + (mi << 4) + fr) << 5) + (fq << 3)];
#pragma unroll
    for (int ni = 0; ni < 4; ++ni)
      bfr[ni] = *(const bf16x8_t*)&Bs[((wc + (ni << 4) + fr) << 5) + (fq << 3)];
#pragma unroll
    for (int mi = 0; mi < 4; ++mi)
#pragma unroll
      for (int ni = 0; ni < 4; ++ni)
        acc[mi][ni] = __builtin_amdgcn_mfma_f32_16x16x32_bf16(af[mi], bfr[ni], acc[mi][ni], 0, 0, 0);
  }
#pragma unroll
  for (int mi = 0; mi < 4; ++mi)
#pragma unroll
    for (int r = 0; r < 4; ++r) {
      const int row = m0 + wr + (mi << 4) + (fq << 2) + r;
      float* crow = C + (size_t)row * DDIM + n0 + wc + fr;
#pragma unroll
      for (int ni = 0; ni < 4; ++ni)
        crow[ni << 4] = acc[mi][ni][r];
    }
}

// ---------------------------------------------------------------------------
// softmax over the size-1 sequence axis == 1.0 exactly -> out = x @ kernel[2].
// ---------------------------------------------------------------------------
extern "C" void kernel_launch(void* const* d_in, const int* in_sizes, int n_in,
                              void* d_out, int out_size, void* d_ws, size_t ws_size,
                              hipStream_t stream) {
  const float* x    = (const float*)d_in[0];
  const float* kern = (const float*)d_in[1];
  const float* W = kern + (size_t)2 * DDIM * DDIM;  // kernel[2] — V projection
  ushort* Wt = (ushort*)d_ws;
  const int M = in_sizes[0] / DDIM;  // 8192

  transpose_w<<<dim3(DDIM / 64, DDIM / 64), 256, 0, stream>>>(W, Wt);

  if (ws_size >= (WT_ELEMS + XB_ELEMS) * sizeof(ushort)) {
    ushort* Xb = (ushort*)d_ws + WT_ELEMS;
    convert_x<<<(unsigned)((size_t)M * DDIM / 8 / 256), 256, 0, stream>>>(x, Xb);
    gemm_bb<<<dim3(M / 128, DDIM / 128), 512, 0, stream>>>(Xb, Wt, (float*)d_out);
  } else {
    gemm_xw<<<dim3(M / 128, DDIM / 128), 256, 0, stream>>>(x, Wt, (float*)d_out);
  }
}

// Round 5
// 111.452 us; speedup vs baseline: 1.1731x; 1.0231x over previous
//
#include <hip/hip_runtime.h>
#include <hip/hip_bf16.h>
#include <stdint.h>

#define AS1 __attribute__((address_space(1)))
#define AS3 __attribute__((address_space(3)))

typedef __attribute__((ext_vector_type(8))) short bf16x8_t;
typedef __attribute__((ext_vector_type(4))) float f32x4_t;

#define DDIM 1024
#define WT_ELEMS ((size_t)DDIM * DDIM)   // 1 Mi bf16 = 2 MiB
#define XB_ELEMS ((size_t)8192 * DDIM)   // 8 Mi bf16 = 16 MiB

// fp32 -> bf16 round-to-nearest-even (truncation bias over K=1024 would eat
// most of the 0.165 absmax budget).
static __device__ inline ushort f32_to_bf16_rne(float f) {
  union { float f; uint32_t u; } v;
  v.f = f;
  v.u += 0x7FFFu + ((v.u >> 16) & 1u);
  return (ushort)(v.u >> 16);
}

// ---------------------------------------------------------------------------
// One-time transpose+convert: Wt[n][k] = bf16(W[k][n]), W fp32 1024x1024.
// ---------------------------------------------------------------------------
__global__ __launch_bounds__(256) void transpose_w(const float* __restrict__ W,
                                                   ushort* __restrict__ Wt) {
  __shared__ float tile[64][65];
  const int t  = threadIdx.x;
  const int bk = blockIdx.x;
  const int bn = blockIdx.y;
#pragma unroll
  for (int s = 0; s < 4; ++s) {
    const int slot = (s << 8) + t;
    const int r    = slot >> 4;
    const int c4   = (slot & 15) << 2;
    const float4 v = *(const float4*)(W + (size_t)(bk * 64 + r) * DDIM + bn * 64 + c4);
    tile[r][c4 + 0] = v.x; tile[r][c4 + 1] = v.y;
    tile[r][c4 + 2] = v.z; tile[r][c4 + 3] = v.w;
  }
  __syncthreads();
#pragma unroll
  for (int s = 0; s < 2; ++s) {
    const int slot = (s << 8) + t;
    const int n    = slot >> 3;
    const int k8   = (slot & 7) << 3;
    union { ushort h[8]; uint4 u; } tmp;
#pragma unroll
    for (int j = 0; j < 8; ++j) tmp.h[j] = f32_to_bf16_rne(tile[k8 + j][n]);
    *(uint4*)(Wt + (size_t)(bn * 64 + n) * DDIM + bk * 64 + k8) = tmp.u;
  }
}

// ---------------------------------------------------------------------------
// One-time convert: Xb = bf16(X), 8192x1024.
// ---------------------------------------------------------------------------
__global__ __launch_bounds__(256) void convert_x(const float* __restrict__ X,
                                                 ushort* __restrict__ Xb) {
  const size_t i = ((size_t)blockIdx.x * 256 + threadIdx.x) << 3;
  const float4 v0 = *(const float4*)(X + i);
  const float4 v1 = *(const float4*)(X + i + 4);
  union { ushort h[8]; uint4 u; } o;
  o.h[0] = f32_to_bf16_rne(v0.x); o.h[1] = f32_to_bf16_rne(v0.y);
  o.h[2] = f32_to_bf16_rne(v0.z); o.h[3] = f32_to_bf16_rne(v0.w);
  o.h[4] = f32_to_bf16_rne(v1.x); o.h[5] = f32_to_bf16_rne(v1.y);
  o.h[6] = f32_to_bf16_rne(v1.z); o.h[7] = f32_to_bf16_rne(v1.w);
  *(uint4*)(Xb + i) = o.u;
}

// ---------------------------------------------------------------------------
// Main GEMM: C[fp32 8192x1024] = Xb * Wt^T.
// 256 threads (4 waves, 2x2 -> 64x64 wave tiles: LDS dup factor 2+2, the
// minimum), 128x128 tile, BK=64, DOUBLE-BUFFERED LDS (2 x 32 KB; 128 KB/CU
// at 2 blocks/CU). Pipeline per iter: issue tile i+1 into buf p^1, compute
// tile i from buf p, barrier. ~1500 cyc of ds_read+MFMA now sits between
// the global_load_lds issue and the barrier's vmcnt(0) drain, hiding the
// ~900-cyc HBM latency that round-4's structure fully exposed.
// Chunk-XOR swizzle (c ^= row&7) keeps ds_read_b128 conflict-free while
// satisfying global_load_lds' wave-uniform-base + lane*16 LDS layout.
// ---------------------------------------------------------------------------
__global__ __launch_bounds__(256, 2) void gemm_bb(const ushort* __restrict__ Xb,
                                                  const ushort* __restrict__ Wt,
                                                  float* __restrict__ C) {
  __shared__ __align__(16) ushort As[2][128 * 64];  // 2 x 16 KB
  __shared__ __align__(16) ushort Bs[2][128 * 64];  // 2 x 16 KB

  const int t    = threadIdx.x;
  const int wave = t >> 6;
  const int lane = t & 63;
  const int m0 = blockIdx.x * 128;
  const int n0 = blockIdx.y * 128;

  // Staging map: thread t covers row sr = t>>3 (0..31) of each 32-row band
  // (4 bands per 128-row tile), swizzled chunk sc = (t&7) ^ (sr&7).
  // (sr + 32j) & 7 == sr & 7, so one sc works for all bands. LDS dest for
  // band j = buf + j*4096 + wave*1024 (+ lane*16 by HW) == slot*16 exactly.
  const int sr = t >> 3;
  const int sc = (t & 7) ^ (sr & 7);
  const ushort* aB = Xb + (size_t)(m0 + sr) * DDIM + (sc << 3);
  const ushort* bB = Wt + (size_t)(n0 + sr) * DDIM + (sc << 3);

  AS3 char* lA = (AS3 char*)&As[0][0];
  AS3 char* lB = (AS3 char*)&Bs[0][0];
  const int woff = wave << 10;

  // Wave tile: 64x64 (m97 shape), 4x4 frags of 16x16x32.
  const int wr = (wave >> 1) << 6;
  const int wc = (wave & 1) << 6;
  const int fr = lane & 15;
  const int fq = lane >> 4;

  f32x4_t acc[4][4] = {};

  auto issue = [&](int kt, int p) {
    const ushort* a = aB + kt;
    const ushort* b = bB + kt;
    AS3 char* dA = lA + (p << 14) + woff;
    AS3 char* dB = lB + (p << 14) + woff;
#pragma unroll
    for (int j = 0; j < 4; ++j) {
      __builtin_amdgcn_global_load_lds((const AS1 void*)(a + (size_t)(j << 5) * DDIM),
                                       (AS3 void*)(dA + (j << 12)), 16, 0, 0);
      __builtin_amdgcn_global_load_lds((const AS1 void*)(b + (size_t)(j << 5) * DDIM),
                                       (AS3 void*)(dB + (j << 12)), 16, 0, 0);
    }
  };

  issue(0, 0);
  __syncthreads();  // buf0 ready

  for (int i = 0; i < 16; ++i) {
    const int p = i & 1;
    if (i < 15) issue((i + 1) << 6, p ^ 1);  // prefetch next tile, other buffer

    const ushort* Ab = &As[p][0];
    const ushort* Bb = &Bs[p][0];
#pragma unroll
    for (int ks = 0; ks < 2; ++ks) {
      const int kc = (ks << 2) + fq;  // chunk 0..7
      bf16x8_t af[4], bfr[4];
#pragma unroll
      for (int mi = 0; mi < 4; ++mi) {
        const int r = wr + (mi << 4) + fr;
        af[mi] = *(const bf16x8_t*)&Ab[(r << 6) + ((kc ^ (r & 7)) << 3)];
      }
#pragma unroll
      for (int ni = 0; ni < 4; ++ni) {
        const int r = wc + (ni << 4) + fr;
        bfr[ni] = *(const bf16x8_t*)&Bb[(r << 6) + ((kc ^ (r & 7)) << 3)];
      }
#pragma unroll
      for (int mi = 0; mi < 4; ++mi)
#pragma unroll
        for (int ni = 0; ni < 4; ++ni)
          acc[mi][ni] = __builtin_amdgcn_mfma_f32_16x16x32_bf16(af[mi], bfr[ni], acc[mi][ni], 0, 0, 0);
    }
    __syncthreads();  // buf p reads done; prefetch (vmcnt) drained -> p^1 full
  }

  // Epilogue. C/D layout: col = lane&15, row = (lane>>4)*4 + reg.
#pragma unroll
  for (int mi = 0; mi < 4; ++mi) {
#pragma unroll
    for (int r = 0; r < 4; ++r) {
      const int row = m0 + wr + (mi << 4) + (fq << 2) + r;
      float* crow = C + (size_t)row * DDIM + n0 + wc + fr;
#pragma unroll
      for (int ni = 0; ni < 4; ++ni)
        crow[ni << 4] = acc[mi][ni][r];
    }
  }
}

// ---------------------------------------------------------------------------
// Fallback GEMM (round-2, known correct) if ws can't hold Wt + Xb.
// ---------------------------------------------------------------------------
__global__ __launch_bounds__(256) void gemm_xw(const float* __restrict__ X,
                                               const ushort* __restrict__ Wt,
                                               float* __restrict__ C) {
  __shared__ __align__(16) ushort As[128 * 32];
  __shared__ __align__(16) ushort Bs[128 * 32];
  const int t    = threadIdx.x;
  const int wave = t >> 6;
  const int lane = t & 63;
  const int m0 = blockIdx.x * 128;
  const int n0 = blockIdx.y * 128;
  const int srow  = (wave << 4) + (lane >> 2);
  const int skcol = (lane & 3) << 3;
  const ushort* bptr0 = Wt + (size_t)(n0 + srow) * DDIM + skcol;
  const ushort* bptr1 = Wt + (size_t)(n0 + 64 + srow) * DDIM + skcol;
  const int ar = t >> 2;
  const int ak = (t & 3) << 3;
  const float* aptr0 = X + (size_t)(m0 + ar) * DDIM + ak;
  const float* aptr1 = X + (size_t)(m0 + 64 + ar) * DDIM + ak;
  ushort* asw0 = &As[(ar << 5) + ak];
  ushort* asw1 = &As[((ar + 64) << 5) + ak];
  const int wr = (wave >> 1) << 6;
  const int wc = (wave & 1) << 6;
  const int fr = lane & 15;
  const int fq = lane >> 4;
  f32x4_t acc[4][4] = {};
  AS3 char* ldsB = (AS3 char*)Bs;
  const int woff = wave << 10;
  for (int kt = 0; kt < DDIM; kt += 32) {
    const float4 a00 = *(const float4*)(aptr0);
    const float4 a01 = *(const float4*)(aptr0 + 4);
    const float4 a10 = *(const float4*)(aptr1);
    const float4 a11 = *(const float4*)(aptr1 + 4);
    aptr0 += 32; aptr1 += 32;
    __syncthreads();
    __builtin_amdgcn_global_load_lds((const AS1 void*)bptr0, (AS3 void*)(ldsB + woff),        16, 0, 0);
    __builtin_amdgcn_global_load_lds((const AS1 void*)bptr1, (AS3 void*)(ldsB + 4096 + woff), 16, 0, 0);
    bptr0 += 32; bptr1 += 32;
    union { ushort h[8]; bf16x8_t v; } c0, c1;
    c0.h[0] = f32_to_bf16_rne(a00.x); c0.h[1] = f32_to_bf16_rne(a00.y);
    c0.h[2] = f32_to_bf16_rne(a00.z); c0.h[3] = f32_to_bf16_rne(a00.w);
    c0.h[4] = f32_to_bf16_rne(a01.x); c0.h[5] = f32_to_bf16_rne(a01.y);
    c0.h[6] = f32_to_bf16_rne(a01.z); c0.h[7] = f32_to_bf16_rne(a01.w);
    c1.h[0] = f32_to_bf16_rne(a10.x); c1.h[1] = f32_to_bf16_rne(a10.y);
    c1.h[2] = f32_to_bf16_rne(a10.z); c1.h[3] = f32_to_bf16_rne(a10.w);
    c1.h[4] = f32_to_bf16_rne(a11.x); c1.h[5] = f32_to_bf16_rne(a11.y);
    c1.h[6] = f32_to_bf16_rne(a11.z); c1.h[7] = f32_to_bf16_rne(a11.w);
    *(bf16x8_t*)asw0 = c0.v;
    *(bf16x8_t*)asw1 = c1.v;
    __syncthreads();
    bf16x8_t af[4], bfr[4];
#pragma unroll
    for (int mi = 0; mi < 4; ++mi)
      af[mi] = *(const bf16x8_t*)&As[((wr + (mi << 4) + fr) << 5) + (fq << 3)];
#pragma unroll
    for (int ni = 0; ni < 4; ++ni)
      bfr[ni] = *(const bf16x8_t*)&Bs[((wc + (ni << 4) + fr) << 5) + (fq << 3)];
#pragma unroll
    for (int mi = 0; mi < 4; ++mi)
#pragma unroll
      for (int ni = 0; ni < 4; ++ni)
        acc[mi][ni] = __builtin_amdgcn_mfma_f32_16x16x32_bf16(af[mi], bfr[ni], acc[mi][ni], 0, 0, 0);
  }
#pragma unroll
  for (int mi = 0; mi < 4; ++mi)
#pragma unroll
    for (int r = 0; r < 4; ++r) {
      const int row = m0 + wr + (mi << 4) + (fq << 2) + r;
      float* crow = C + (size_t)row * DDIM + n0 + wc + fr;
#pragma unroll
      for (int ni = 0; ni < 4; ++ni)
        crow[ni << 4] = acc[mi][ni][r];
    }
}

// ---------------------------------------------------------------------------
// softmax over the size-1 sequence axis == 1.0 exactly -> out = x @ kernel[2].
// ---------------------------------------------------------------------------
extern "C" void kernel_launch(void* const* d_in, const int* in_sizes, int n_in,
                              void* d_out, int out_size, void* d_ws, size_t ws_size,
                              hipStream_t stream) {
  const float* x    = (const float*)d_in[0];
  const float* kern = (const float*)d_in[1];
  const float* W = kern + (size_t)2 * DDIM * DDIM;  // kernel[2] — V projection
  ushort* Wt = (ushort*)d_ws;
  const int M = in_sizes[0] / DDIM;  // 8192

  transpose_w<<<dim3(DDIM / 64, DDIM / 64), 256, 0, stream>>>(W, Wt);

  if (ws_size >= (WT_ELEMS + XB_ELEMS) * sizeof(ushort)) {
    ushort* Xb = (ushort*)d_ws + WT_ELEMS;
    convert_x<<<(unsigned)((size_t)M * DDIM / 8 / 256), 256, 0, stream>>>(x, Xb);
    gemm_bb<<<dim3(M / 128, DDIM / 128), 256, 0, stream>>>(Xb, Wt, (float*)d_out);
  } else {
    gemm_xw<<<dim3(M / 128, DDIM / 128), 256, 0, stream>>>(x, Wt, (float*)d_out);
  }
}